// Round 5
// baseline (365.198 us; speedup 1.0000x reference)
//
#include <hip/hip_runtime.h>
#include <hip/hip_bf16.h>

#define HID 96
#define INDIM 128
#define OUTDIM 64
#define BM 128
#define GP 128     // partial/scatter grid blocks (fixed mapping)
#define NBF 512    // max bins for CSR build (shift>=7)

typedef __attribute__((ext_vector_type(8))) _Float16 half8;
typedef __attribute__((ext_vector_type(4))) _Float16 half4;
typedef __attribute__((ext_vector_type(4))) float floatx4;
typedef __attribute__((ext_vector_type(4))) unsigned int uintx4;

__device__ __forceinline__ float ldmix(const void* p, long i, int mode) {
    return mode ? ((const float*)p)[i]
                : __bfloat162float(((const __hip_bfloat16*)p)[i]);
}

// ---------------- dtype sniffer (parallel: 64 lanes x 64 words) ----------------
__global__ void sniff_kernel(const unsigned int* xw, int* mode) {
    int lane = threadIdx.x & 63;
    int cnt = 0;
    for (int i = lane; i < 4096; i += 64) {
        unsigned int low = xw[i] & 0xFFFFu;
        unsigned int e = (low >> 7) & 0xFFu;
        if (e >= 0xC0u) cnt++;
    }
    #pragma unroll
    for (int ofs = 32; ofs > 0; ofs >>= 1) cnt += __shfl_down(cnt, ofs);
    if (lane == 0) *mode = (cnt > 256) ? 1 : 0;  // 1 = fp32 inputs, 0 = bf16 inputs
}

// ---------------- weight prep (fp16 planes) ----------------
// smallf: [0..95] b_in, [96..383] bih, [384..671] bhh, [672..735] b_out,
//         [736..751] tau_w2, [752..767] tau_b1, [768] tau_b2
__global__ void prep_kernel(const void* w_in, const void* b_in, const void* tau_w1,
                            const void* tau_b1, const void* tau_w2, const void* tau_b2,
                            const void* wih, const void* whh, const void* bih, const void* bhh,
                            const void* w_out, const void* b_out,
                            _Float16* W2F, _Float16* WinF, _Float16* WoutF,
                            float* tau_w1_f, float* smallf, const int* mode) {
    int m = *mode;
    int tid = blockIdx.x*blockDim.x + threadIdx.x;
    if (tid < 384*192) {
        int c = tid / 192, k = tid % 192;
        int g = c / 96, jj = c % 96;
        float v = 0.f;
        if (k < 96) {
            if (g == 0)      v = ldmix(wih, (long)(jj)*96 + k, m);
            else if (g == 1) v = ldmix(wih, (long)(96+jj)*96 + k, m);
            else if (g == 2) v = ldmix(wih, (long)(192+jj)*96 + k, m);
        } else {
            int kk = k - 96;
            if (g == 0)      v = ldmix(whh, (long)(jj)*96 + kk, m);
            else if (g == 1) v = ldmix(whh, (long)(96+jj)*96 + kk, m);
            else if (g == 3) v = ldmix(whh, (long)(192+jj)*96 + kk, m);
        }
        W2F[tid] = (_Float16)v;
    }
    if (tid < 96*128) {
        int j = tid >> 7, k = tid & 127;
        WinF[tid] = (_Float16)ldmix(w_in, (long)k*96 + j, m);
    }
    if (tid < 64*96) {
        int j = tid / 96, k = tid % 96;
        WoutF[tid] = (_Float16)ldmix(w_out, (long)k*OUTDIM + j, m);
    }
    if (tid < INDIM*16)   tau_w1_f[tid] = ldmix(tau_w1, tid, m);
    if (tid < HID)    smallf[tid]       = ldmix(b_in, tid, m);
    if (tid < 3*HID){ smallf[96+tid]    = ldmix(bih, tid, m);
                      smallf[384+tid]   = ldmix(bhh, tid, m); }
    if (tid < OUTDIM) smallf[672+tid]   = ldmix(b_out, tid, m);
    if (tid < 16)   { smallf[736+tid]   = ldmix(tau_w2, tid, m);
                      smallf[752+tid]   = ldmix(tau_b1, tid, m); }
    if (tid == 0)     smallf[768]       = ldmix(tau_b2, 0, m);
}

// ---------------- h0 = relu(x @ w_in + b_in): one block computes ALL 96 cols ----------------
__global__ void __launch_bounds__(512) h0_kernel(
        const void* __restrict__ x, const _Float16* __restrict__ WinF,
        const float* __restrict__ smallf, const int* __restrict__ mode,
        _Float16* __restrict__ hN, int N) {
    int row0 = blockIdx.x * BM;

    __shared__ _Float16 Ah[128*136];
    __shared__ _Float16 Wh[96*136];

    int tid = threadIdx.x;
    int m = *mode;
    long limit = (long)N * INDIM;
    #pragma unroll
    for (int j = 0; j < 8; j++) {
        int e = (tid + j*512) * 4;
        int r = e >> 7, c = e & 127;
        long ge = (long)(row0 + r)*INDIM + c;
        half4 vh = {0, 0, 0, 0};
        if (ge + 4 <= limit) {
            if (m) {
                floatx4 v = *(const floatx4*)((const float*)x + ge);
                #pragma unroll
                for (int q = 0; q < 4; q++) vh[q] = (_Float16)v[q];
            } else {
                const __hip_bfloat16* p = (const __hip_bfloat16*)x + ge;
                #pragma unroll
                for (int q = 0; q < 4; q++) vh[q] = (_Float16)__bfloat162float(p[q]);
            }
        }
        *(half4*)(&Ah[r*136 + c]) = vh;
    }
    #pragma unroll
    for (int j = 0; j < 3; j++) {
        int idx = tid + j*512;          // < 1536 = 96 rows x 16 half8
        int wrow = idx >> 4;
        int k = (idx & 15) * 8;
        *(half8*)(&Wh[wrow*136 + k]) = *(const half8*)(WinF + (long)wrow*INDIM + k);
    }
    __syncthreads();

    int lane = tid & 63;
    int w = tid >> 6;
    int m15 = lane & 15, quad = lane >> 4;
    int abase = (w*16 + m15)*136 + quad*8;
    half8 a0 = *(const half8*)(&Ah[abase]);
    half8 a1 = *(const half8*)(&Ah[abase + 32]);
    half8 a2 = *(const half8*)(&Ah[abase + 64]);
    half8 a3 = *(const half8*)(&Ah[abase + 96]);

    #pragma unroll
    for (int jt = 0; jt < 6; jt++) {
        floatx4 acc = {0.f, 0.f, 0.f, 0.f};
        int wb = (jt*16 + m15)*136 + quad*8;
        acc = __builtin_amdgcn_mfma_f32_16x16x32_f16(a0, *(const half8*)(&Wh[wb]),      acc, 0, 0, 0);
        acc = __builtin_amdgcn_mfma_f32_16x16x32_f16(a1, *(const half8*)(&Wh[wb+32]),   acc, 0, 0, 0);
        acc = __builtin_amdgcn_mfma_f32_16x16x32_f16(a2, *(const half8*)(&Wh[wb+64]),   acc, 0, 0, 0);
        acc = __builtin_amdgcn_mfma_f32_16x16x32_f16(a3, *(const half8*)(&Wh[wb+96]),   acc, 0, 0, 0);
        int jj = jt*16 + m15;
        float b = smallf[jj];
        #pragma unroll
        for (int reg = 0; reg < 4; reg++) {
            int li = row0 + w*16 + quad*4 + reg;
            if (li < N) hN[(long)li*HID + jj] = (_Float16)fmaxf(acc[reg] + b, 0.f);
        }
    }
}

// ---------------- tau MLP -> steps (thread-per-node, x row in registers, weights via SMEM broadcast) ----------------
__global__ void __launch_bounds__(256) tau_kernel(
        const void* __restrict__ x, const float* __restrict__ tw,
        const float* __restrict__ smallf, const int* __restrict__ mode,
        int* __restrict__ steps, int N) {
    int n = blockIdx.x*blockDim.x + threadIdx.x;
    int m = *mode;
    int nc = (n < N) ? n : (N - 1);   // clamp: inactive lanes load valid memory

    float xr[128];
    if (m) {
        const floatx4* xp = (const floatx4*)x + (size_t)nc*32;
        #pragma unroll
        for (int ks = 0; ks < 32; ks++) {
            floatx4 v = xp[ks];
            xr[ks*4+0] = v[0]; xr[ks*4+1] = v[1];
            xr[ks*4+2] = v[2]; xr[ks*4+3] = v[3];
        }
    } else {
        const uintx4* xp = (const uintx4*)((const __hip_bfloat16*)x + (size_t)nc*128);
        #pragma unroll
        for (int ks = 0; ks < 16; ks++) {
            uintx4 v = xp[ks];
            #pragma unroll
            for (int q = 0; q < 4; q++) {
                unsigned int w = v[q];
                xr[ks*8 + q*2 + 0] = __uint_as_float((w & 0xFFFFu) << 16);
                xr[ks*8 + q*2 + 1] = __uint_as_float(w & 0xFFFF0000u);
            }
        }
    }

    float acc[16];
    #pragma unroll
    for (int j = 0; j < 16; j++) acc[j] = 0.f;
    #pragma unroll
    for (int k = 0; k < 128; k++) {
        float xv = xr[k];
        #pragma unroll
        for (int j = 0; j < 16; j++) acc[j] += xv * tw[k*16 + j];
    }

    float z = smallf[768];
    #pragma unroll
    for (int j = 0; j < 16; j++)
        z += fmaxf(acc[j] + smallf[752 + j], 0.f) * smallf[736 + j];
    float tau = fmaxf(z, 0.f) + log1pf(expf(-fabsf(z)));   // stable softplus
    float inv = 1.0f / tau;
    int s;
    if (inv >= 5.0f) s = 5;
    else { s = (int)inv; if (s < 0) s = 0; if (s > 5) s = 5; }
    if (n < N) steps[n] = s;
}

// ---------------- binned CSR build ----------------
// bin = row >> shift (shift=7 -> 128 nodes/bin). Packed edge: (local_row<<24) | col.
__global__ void __launch_bounds__(512) bincnt_kernel(
        const int* __restrict__ row, int E, int NB, int shift, int* __restrict__ bincnt) {
    __shared__ int h[NBF];
    int tid = threadIdx.x;
    int bs = blockDim.x;
    for (int i = tid; i < NB; i += bs) h[i] = 0;
    __syncthreads();
    int stride = gridDim.x * bs;
    for (int e = blockIdx.x*bs + tid; e < E; e += stride)
        atomicAdd(&h[row[e] >> shift], 1);
    __syncthreads();
    for (int i = tid; i < NB; i += bs) {
        int c = h[i];
        if (c) atomicAdd(&bincnt[i], c);
    }
}

__global__ void binscan_kernel(const int* __restrict__ bincnt, int NB, int E, int N,
                               int* __restrict__ bin_start, int* __restrict__ bincur,
                               int* __restrict__ off) {
    __shared__ int vals[NBF];
    __shared__ int part[256];
    int tid = threadIdx.x;
    int per = (NB + 255) / 256;
    int base = tid * per;
    int s = 0;
    for (int j = 0; j < per; j++) {
        int i = base + j;
        int v = (i < NB) ? bincnt[i] : 0;
        if (i < NBF) vals[i] = s;
        s += v;
    }
    part[tid] = s;
    __syncthreads();
    for (int ofs = 1; ofs < 256; ofs <<= 1) {
        int t = (tid >= ofs) ? part[tid - ofs] : 0;
        __syncthreads();
        part[tid] += t;
        __syncthreads();
    }
    int add = (tid == 0) ? 0 : part[tid - 1];
    for (int j = 0; j < per; j++) {
        int i = base + j;
        if (i < NB) {
            int v = vals[i] + add;
            bin_start[i] = v;
            bincur[i] = v;
        }
    }
    if (tid == 0) { bin_start[NB] = E; off[N] = E; }
}

__global__ void __launch_bounds__(512) binfill_kernel(
        const int* __restrict__ row, const int* __restrict__ col,
        int E, int NB, int shift, int* __restrict__ bincur,
        unsigned int* __restrict__ binbuf) {
    __shared__ int h[NBF];
    __shared__ int bs[NBF];
    int tid = threadIdx.x;
    int bsz = blockDim.x;
    int chunk = (E + gridDim.x - 1) / gridDim.x;
    int c0 = blockIdx.x * chunk;
    int c1 = min(c0 + chunk, E);
    for (int i = tid; i < NB; i += bsz) h[i] = 0;
    __syncthreads();
    for (int e = c0 + tid; e < c1; e += bsz)
        atomicAdd(&h[row[e] >> shift], 1);
    __syncthreads();
    for (int i = tid; i < NB; i += bsz) {
        int c = h[i];
        if (c) { bs[i] = atomicAdd(&bincur[i], c); h[i] = 0; }
    }
    __syncthreads();
    unsigned int mask = (1u << shift) - 1u;
    for (int e = c0 + tid; e < c1; e += bsz) {
        int r = row[e];
        int b = r >> shift;
        int p = atomicAdd(&h[b], 1);
        binbuf[bs[b] + p] = ((unsigned int)(r & mask) << 24) | (unsigned int)col[e];
    }
}

__global__ void __launch_bounds__(256) bincsr_kernel(
        const unsigned int* __restrict__ binbuf,
        const int* __restrict__ bin_start, int N, int shift,
        int* __restrict__ off, int* __restrict__ csr_col) {
    __shared__ int hist[256];
    __shared__ int pfx[256];
    int b = blockIdx.x;
    int tid = threadIdx.x;
    int BINSZ = 1 << shift;
    int s0 = bin_start[b], s1 = bin_start[b + 1];
    if (tid < BINSZ) hist[tid] = 0;
    __syncthreads();
    for (int e = s0 + tid; e < s1; e += 256)
        atomicAdd(&hist[binbuf[e] >> 24], 1);
    __syncthreads();
    if (tid == 0) {
        int run = 0;
        for (int j = 0; j < BINSZ; j++) { pfx[j] = run; run += hist[j]; }
    }
    __syncthreads();
    if (tid < BINSZ) {
        int node = (b << shift) + tid;
        if (node < N) off[node] = s0 + pfx[tid];
        hist[tid] = pfx[tid];   // cursor starts at local prefix
    }
    __syncthreads();
    for (int e = s0 + tid; e < s1; e += 256) {
        unsigned int pk = binbuf[e];
        int lr = pk >> 24;
        int p = atomicAdd(&hist[lr], 1);
        csr_col[s0 + p] = (int)(pk & 0xFFFFFFu);
    }
}

// ---------------- multi-block deterministic bucket pipeline (steps only) ----------------
__global__ void partial_kernel(const int* __restrict__ steps, int N, int C,
                               int* __restrict__ blksum) {
    __shared__ int red[256*8];
    int tid = threadIdx.x;
    int tg = blockIdx.x*256 + tid;
    int start = tg*C, end = min(start + C, N);
    if (end < start) end = start;
    int cnt[6] = {0,0,0,0,0,0};
    for (int i = start; i < end; i++) cnt[steps[i]]++;
    #pragma unroll
    for (int k = 0; k < 6; k++) red[tid*8 + k] = cnt[k];
    __syncthreads();
    for (int ofs = 128; ofs > 0; ofs >>= 1) {
        if (tid < ofs) {
            #pragma unroll
            for (int k = 0; k < 6; k++) red[tid*8 + k] += red[(tid+ofs)*8 + k];
        }
        __syncthreads();
    }
    if (tid < 6) blksum[blockIdx.x*8 + tid] = red[tid];
}

__global__ void base_kernel(const int* __restrict__ blksum, int* __restrict__ bstart,
                            int* __restrict__ blkbase) {
    __shared__ int tot[8];
    __shared__ int sb[8];
    int tid = threadIdx.x;
    if (tid < 6) {
        int s = 0;
        for (int b = 0; b < GP; b++) s += blksum[b*8 + tid];
        tot[tid] = s;
    }
    __syncthreads();
    if (tid == 0) {
        int run = 0;
        for (int ss = 5; ss >= 0; --ss) { sb[ss] = run; bstart[ss] = run; run += tot[ss]; }
        bstart[6] = run;          // = N
    }
    __syncthreads();
    if (tid < 6) {
        int run = sb[tid];
        for (int b = 0; b < GP; b++) { blkbase[b*8 + tid] = run; run += blksum[b*8 + tid]; }
    }
}

__global__ void scatter_kernel(const int* __restrict__ steps, const int* __restrict__ blkbase,
                               int N, int C, int* __restrict__ order) {
    __shared__ int buf[256];
    int tid = threadIdx.x;
    int b = blockIdx.x;
    int tg = b*256 + tid;
    int start = tg*C, end = min(start + C, N);
    if (end < start) end = start;
    int cnt[6] = {0,0,0,0,0,0};
    for (int i = start; i < end; i++) cnt[steps[i]]++;
    int mybase[6];
    #pragma unroll
    for (int k = 0; k < 6; k++) {
        buf[tid] = cnt[k];
        __syncthreads();
        for (int ofs = 1; ofs < 256; ofs <<= 1) {
            int t = (tid >= ofs) ? buf[tid - ofs] : 0;
            __syncthreads();
            buf[tid] += t;
            __syncthreads();
        }
        mybase[k] = blkbase[b*8 + k] + buf[tid] - cnt[k];
        __syncthreads();
    }
    for (int i = start; i < end; i++) order[mybase[steps[i]]++] = i;
}

// ---------------- pack hN into order-space fp16 plane (half8 vectorized) ----------------
__global__ void pack_kernel(const _Float16* __restrict__ hN, const int* __restrict__ order,
                            _Float16* __restrict__ hF, int N) {
    int tid = blockIdx.x*blockDim.x + threadIdx.x;
    if (tid >= N*12) return;
    int li = tid / 12, fg = tid % 12;
    int n = order[li];
    *(half8*)(hF + (size_t)li*HID + fg*8) = *(const half8*)(hN + (size_t)n*HID + fg*8);
}

// ---------------- aggregation: half8 gathers (16B/lane), fp32 accumulate -> packed fp16 aggF ----------------
__global__ void agg_kernel(const _Float16* __restrict__ hN, const int* __restrict__ off,
                           const int* __restrict__ csr_col, const int* __restrict__ order,
                           const int* __restrict__ bstart, int t, _Float16* __restrict__ aggF) {
    int K = bstart[t];
    int total = K * 12;                       // 12 half8 groups per node
    int stride = gridDim.x * blockDim.x;
    for (int idx = blockIdx.x*blockDim.x + threadIdx.x; idx < total; idx += stride) {
        int li = idx / 12, fg = idx % 12;
        int f = fg * 8;
        int i = order[li];
        half8 hv = *(const half8*)(hN + (size_t)i*HID + f);
        float hvf[8];
        #pragma unroll
        for (int q = 0; q < 8; q++) hvf[q] = (float)hv[q];
        int e0 = off[i], e1 = off[i+1];
        float acc[8];
        #pragma unroll
        for (int q = 0; q < 8; q++) acc[q] = 0.f;
        int e = e0;
        for (; e + 4 <= e1; e += 4) {
            int c0 = csr_col[e],   c1 = csr_col[e+1];
            int c2 = csr_col[e+2], c3 = csr_col[e+3];
            half8 v0 = *(const half8*)(hN + (size_t)c0*HID + f);
            half8 v1 = *(const half8*)(hN + (size_t)c1*HID + f);
            half8 v2 = *(const half8*)(hN + (size_t)c2*HID + f);
            half8 v3 = *(const half8*)(hN + (size_t)c3*HID + f);
            #pragma unroll
            for (int q = 0; q < 8; q++) {
                acc[q] += fabsf(hvf[q] - (float)v0[q]) + fabsf(hvf[q] - (float)v1[q])
                        + fabsf(hvf[q] - (float)v2[q]) + fabsf(hvf[q] - (float)v3[q]);
            }
        }
        for (; e < e1; e++) {
            int c = csr_col[e];
            half8 v = *(const half8*)(hN + (size_t)c*HID + f);
            #pragma unroll
            for (int q = 0; q < 8; q++) acc[q] += fabsf(hvf[q] - (float)v[q]);
        }
        half8 outv;
        #pragma unroll
        for (int q = 0; q < 8; q++) outv[q] = (_Float16)acc[q];
        *(half8*)(aggF + (size_t)li*HID + f) = outv;
    }
}

// ---------------- GRU: one block computes ALL 96 cols; A staged once, W streamed ----------------
__global__ void __launch_bounds__(512) gru_kernel(
        const _Float16* __restrict__ aggF, const _Float16* __restrict__ hFin,
        const _Float16* __restrict__ W2F,
        const float* __restrict__ smallf, const int* __restrict__ bstart, int t,
        const int* __restrict__ order, _Float16* __restrict__ hN,
        _Float16* __restrict__ hFout, int N) {
    int K = bstart[t];
    int row0 = blockIdx.x * BM;
    if (row0 >= K) return;

    __shared__ _Float16 Ah[128*200];   // [agg|h] 128 x (192+8)
    __shared__ _Float16 Wh[64*200];    // current col-tile's 64 W-rows (4 gates x 16 cols)

    int tid = threadIdx.x;
    long limit = (long)N * HID;
    #pragma unroll
    for (int j = 0; j < 3; j++) {
        int e = (tid + j*512) * 8;     // 12288 elems = 128 x 96
        int r = e / 96, c = e % 96;
        long ge = (long)(row0 + r)*96 + c;
        half8 va = {0,0,0,0,0,0,0,0}, vh = va;
        if (ge + 8 <= limit) {
            va = *(const half8*)(aggF + ge);
            vh = *(const half8*)(hFin + ge);
        }
        *(half8*)(&Ah[r*200 + c])      = va;
        *(half8*)(&Ah[r*200 + 96 + c]) = vh;
    }
    // stage W chunk for jt=0
    #pragma unroll
    for (int j = 0; j < 3; j++) {
        int idx = tid + j*512;         // < 1536 = 64 rows x 24 half8
        int wl = idx / 24;
        int kk = (idx % 24) * 8;
        int g = wl >> 4, cc = wl & 15;
        *(half8*)(&Wh[wl*200 + kk]) = *(const half8*)(W2F + (long)(g*96 + cc)*192 + kk);
    }
    __syncthreads();

    int lane = tid & 63;
    int w = tid >> 6;
    int m15 = lane & 15, quad = lane >> 4;
    int abase = (w*16 + m15)*200 + quad*8;
    half8 a[6];
    #pragma unroll
    for (int ks = 0; ks < 6; ks++) a[ks] = *(const half8*)(&Ah[abase + ks*32]);

    #pragma unroll
    for (int jt = 0; jt < 6; jt++) {
        floatx4 acc[4];
        #pragma unroll
        for (int g = 0; g < 4; g++) acc[g] = (floatx4){0.f, 0.f, 0.f, 0.f};
        #pragma unroll
        for (int ks = 0; ks < 6; ks++) {
            int k0 = ks*32;
            #pragma unroll
            for (int g = 0; g < 4; g++) {
                half8 b = *(const half8*)(&Wh[(g*16 + m15)*200 + quad*8 + k0]);
                acc[g] = __builtin_amdgcn_mfma_f32_16x16x32_f16(a[ks], b, acc[g], 0, 0, 0);
            }
        }

        int jj = jt*16 + m15;
        float bir = smallf[96+jj],  biz = smallf[192+jj], bin = smallf[288+jj];
        float bhr = smallf[384+jj], bhz = smallf[480+jj], bhn = smallf[576+jj];
        #pragma unroll
        for (int reg = 0; reg < 4; reg++) {
            int li = row0 + w*16 + quad*4 + reg;
            if (li < K) {
                float rp = acc[0][reg] + bir + bhr;
                float zp = acc[1][reg] + biz + bhz;
                float ip = acc[2][reg] + bin;
                float hn = acc[3][reg] + bhn;
                float r  = 1.f/(1.f + expf(-rp));
                float z  = 1.f/(1.f + expf(-zp));
                float nn = tanhf(ip + r*hn);
                int tr = w*16 + quad*4 + reg;             // row within tile
                float hold = (float)Ah[tr*200 + 96 + jj]; // h_old from LDS A-tile
                _Float16 v16 = (_Float16)((1.f - z)*nn + z*hold);
                int node = order[li];
                hN[(long)node*HID + jj] = v16;
                hFout[(long)li*HID + jj] = v16;
            }
        }

        if (jt < 5) {
            __syncthreads();   // all waves done reading Wh
            #pragma unroll
            for (int j = 0; j < 3; j++) {
                int idx = tid + j*512;
                int wl = idx / 24;
                int kk = (idx % 24) * 8;
                int g = wl >> 4, cc = wl & 15;
                *(half8*)(&Wh[wl*200 + kk]) =
                    *(const half8*)(W2F + (long)(g*96 + (jt+1)*16 + cc)*192 + kk);
            }
            __syncthreads();   // Wh ready
        }
    }
}

// ---------------- out = h @ w_out + b_out: one block computes ALL 64 cols ----------------
__global__ void __launch_bounds__(512) out_kernel(
        const _Float16* __restrict__ hN, const _Float16* __restrict__ WoutF,
        const float* __restrict__ smallf, void* out, const int* mode, int N) {
    int row0 = blockIdx.x * BM;

    __shared__ _Float16 Ah[128*104];
    __shared__ _Float16 Wh[64*104];

    int tid = threadIdx.x;
    long limit = (long)N * HID;
    #pragma unroll
    for (int j = 0; j < 3; j++) {
        int e = (tid + j*512) * 8;        // 12288 elems per tile
        int r = e / 96, c = e % 96;
        long ge = (long)(row0 + r)*HID + c;
        half8 v = {0,0,0,0,0,0,0,0};
        if (ge + 8 <= limit) v = *(const half8*)(hN + ge);
        *(half8*)(&Ah[r*104 + c]) = v;
    }
    #pragma unroll
    for (int j = 0; j < 2; j++) {
        int idx = tid + j*512;            // < 768 = 64 rows x 12 half8
        if (idx < 768) {
            int wrow = idx / 12;
            int k = (idx % 12) * 8;
            *(half8*)(&Wh[wrow*104 + k]) = *(const half8*)(WoutF + (long)wrow*HID + k);
        }
    }
    __syncthreads();

    int lane = tid & 63;
    int w = tid >> 6;
    int m15 = lane & 15, quad = lane >> 4;
    int abase = (w*16 + m15)*104 + quad*8;
    half8 a0 = *(const half8*)(&Ah[abase]);
    half8 a1 = *(const half8*)(&Ah[abase + 32]);
    half8 a2 = *(const half8*)(&Ah[abase + 64]);
    int m = *mode;

    #pragma unroll
    for (int jt = 0; jt < 4; jt++) {
        floatx4 acc = {0.f, 0.f, 0.f, 0.f};
        int wb = (jt*16 + m15)*104 + quad*8;
        acc = __builtin_amdgcn_mfma_f32_16x16x32_f16(a0, *(const half8*)(&Wh[wb]),    acc, 0, 0, 0);
        acc = __builtin_amdgcn_mfma_f32_16x16x32_f16(a1, *(const half8*)(&Wh[wb+32]), acc, 0, 0, 0);
        acc = __builtin_amdgcn_mfma_f32_16x16x32_f16(a2, *(const half8*)(&Wh[wb+64]), acc, 0, 0, 0);
        int jj = jt*16 + m15;
        float b = smallf[672+jj];
        #pragma unroll
        for (int reg = 0; reg < 4; reg++) {
            int li = row0 + w*16 + quad*4 + reg;
            if (li < N) {
                float v = acc[reg] + b;
                long oi = (long)li*OUTDIM + jj;
                if (m) ((float*)out)[oi] = v;
                else   ((__hip_bfloat16*)out)[oi] = __float2bfloat16(v);
            }
        }
    }
}

extern "C" void kernel_launch(void* const* d_in, const int* in_sizes, int n_in,
                              void* d_out, int out_size, void* d_ws, size_t ws_size,
                              hipStream_t stream) {
    const void* x      = d_in[0];
    const int*  ei     = (const int*)d_in[1];
    const void* w_in   = d_in[2],  *b_in   = d_in[3];
    const void* tau_w1 = d_in[4],  *tau_b1 = d_in[5];
    const void* tau_w2 = d_in[6],  *tau_b2 = d_in[7];
    const void* wih    = d_in[8],  *whh    = d_in[9];
    const void* bih    = d_in[10], *bhh    = d_in[11];
    const void* w_out  = d_in[12], *b_out  = d_in[13];

    int N = in_sizes[0] / INDIM;
    int E = in_sizes[1] / 2;
    const int* row = ei;
    const int* col = ei + E;

    // bin sizing: 128 nodes/bin (shift=7); widen if N too large for NBF bins
    int shift = 7;
    while ((((N + (1 << shift) - 1) >> shift)) > NBF && shift < 8) shift++;
    int NB = (N + (1 << shift) - 1) >> shift;

    char* ws = (char*)d_ws;
    size_t o = 0;
    auto take = [&](size_t bytes) -> char* {
        char* p = ws + o;
        o = (o + bytes + 255) & ~(size_t)255;
        return p;
    };
    _Float16* hN    = (_Float16*)take((size_t)N*HID*2);
    _Float16* hFa   = (_Float16*)take((size_t)N*HID*2);
    _Float16* hFb   = (_Float16*)take((size_t)N*HID*2);
    _Float16* aggF  = (_Float16*)take((size_t)N*HID*2);
    _Float16* W2F   = (_Float16*)take((size_t)384*192*2);
    _Float16* WinF  = (_Float16*)take((size_t)96*128*2);
    _Float16* WoutF = (_Float16*)take((size_t)64*96*2);
    float* tau_w1_f = (float*)take((size_t)INDIM*16*4);
    float* smallf   = (float*)take(1024*4);
    int*   off      = (int*)take((size_t)(N+1)*4);
    int*   csr_col  = (int*)take((size_t)E*4);
    int*   order    = (int*)take((size_t)N*4);
    int*   steps    = (int*)take((size_t)N*4);
    int*   bstart   = (int*)take(64);
    int*   mode     = (int*)take(64);
    int*   blksum   = (int*)take((size_t)GP*8*4);
    int*   blkbase  = (int*)take((size_t)GP*8*4);
    unsigned int* binbuf = (unsigned int*)take((size_t)E*4);
    int*   bin_start = (int*)take((size_t)(NBF+1)*4);
    int*   bincur    = (int*)take((size_t)NBF*4);
    char*  zbase    = ws + o;
    int*   bincnt   = (int*)take((size_t)NBF*4);
    size_t zbytes   = (size_t)((ws + o) - zbase);

    hipMemsetAsync(zbase, 0, zbytes, stream);
    sniff_kernel<<<1, 64, 0, stream>>>((const unsigned int*)x, mode);

    prep_kernel<<<(384*192 + 255)/256, 256, 0, stream>>>(
        w_in, b_in, tau_w1, tau_b1, tau_w2, tau_b2, wih, whh, bih, bhh, w_out, b_out,
        W2F, WinF, WoutF, tau_w1_f, smallf, mode);

    int gx = (N + BM - 1)/BM;
    h0_kernel<<<gx, 512, 0, stream>>>(x, WinF, smallf, mode, hN, N);
    tau_kernel<<<(N + 255)/256, 256, 0, stream>>>(x, tau_w1_f, smallf, mode, steps, N);

    // binned CSR build
    bincnt_kernel<<<256, 512, 0, stream>>>(row, E, NB, shift, bincnt);
    binscan_kernel<<<1, 256, 0, stream>>>(bincnt, NB, E, N, bin_start, bincur, off);
    binfill_kernel<<<256, 512, 0, stream>>>(row, col, E, NB, shift, bincur, binbuf);
    bincsr_kernel<<<NB, 256, 0, stream>>>(binbuf, bin_start, N, shift, off, csr_col);

    int C = (N + GP*256 - 1) / (GP*256);
    partial_kernel<<<GP, 256, 0, stream>>>(steps, N, C, blksum);
    base_kernel<<<1, 64, 0, stream>>>(blksum, bstart, blkbase);
    scatter_kernel<<<GP, 256, 0, stream>>>(steps, blkbase, N, C, order);

    pack_kernel<<<(N*12 + 255)/256, 256, 0, stream>>>(hN, order, hFa, N);

    _Float16* hin = hFa;
    _Float16* hout = hFb;
    for (int t = 0; t < 5; t++) {
        agg_kernel<<<4096, 256, 0, stream>>>(hN, off, csr_col, order, bstart, t, aggF);
        gru_kernel<<<gx, 512, 0, stream>>>(aggF, hin, W2F, smallf, bstart, t,
                                           order, hN, hout, N);
        _Float16* tmp = hin; hin = hout; hout = tmp;
    }

    out_kernel<<<gx, 512, 0, stream>>>(hN, WoutF, smallf, d_out, mode, N);
}

// Round 6
// 339.791 us; speedup vs baseline: 1.0748x; 1.0748x over previous
//
#include <hip/hip_runtime.h>
#include <hip/hip_bf16.h>

#define HID 96
#define INDIM 128
#define OUTDIM 64
#define BM 128
#define GP 128     // partial/scatter grid blocks (fixed mapping)
#define NBF 512    // max bins for CSR build (shift>=7)

typedef __attribute__((ext_vector_type(8))) _Float16 half8;
typedef __attribute__((ext_vector_type(4))) _Float16 half4;
typedef __attribute__((ext_vector_type(4))) float floatx4;
typedef __attribute__((ext_vector_type(4))) unsigned int uintx4;

__device__ __forceinline__ float ldmix(const void* p, long i, int mode) {
    return mode ? ((const float*)p)[i]
                : __bfloat162float(((const __hip_bfloat16*)p)[i]);
}

// ---------------- dtype sniffer (parallel: 64 lanes x 64 words) ----------------
__global__ void sniff_kernel(const unsigned int* xw, int* mode) {
    int lane = threadIdx.x & 63;
    int cnt = 0;
    for (int i = lane; i < 4096; i += 64) {
        unsigned int low = xw[i] & 0xFFFFu;
        unsigned int e = (low >> 7) & 0xFFu;
        if (e >= 0xC0u) cnt++;
    }
    #pragma unroll
    for (int ofs = 32; ofs > 0; ofs >>= 1) cnt += __shfl_down(cnt, ofs);
    if (lane == 0) *mode = (cnt > 256) ? 1 : 0;  // 1 = fp32 inputs, 0 = bf16 inputs
}

// ---------------- weight prep (fp16 planes) ----------------
// smallf: [0..95] b_in, [96..383] bih, [384..671] bhh, [672..735] b_out,
//         [736..751] tau_w2, [752..767] tau_b1, [768] tau_b2
__global__ void prep_kernel(const void* w_in, const void* b_in, const void* tau_w1,
                            const void* tau_b1, const void* tau_w2, const void* tau_b2,
                            const void* wih, const void* whh, const void* bih, const void* bhh,
                            const void* w_out, const void* b_out,
                            _Float16* W2F, _Float16* WinF, _Float16* WoutF,
                            float* tau_w1_f, float* smallf, const int* mode) {
    int m = *mode;
    int tid = blockIdx.x*blockDim.x + threadIdx.x;
    if (tid < 384*192) {
        int c = tid / 192, k = tid % 192;
        int g = c / 96, jj = c % 96;
        float v = 0.f;
        if (k < 96) {
            if (g == 0)      v = ldmix(wih, (long)(jj)*96 + k, m);
            else if (g == 1) v = ldmix(wih, (long)(96+jj)*96 + k, m);
            else if (g == 2) v = ldmix(wih, (long)(192+jj)*96 + k, m);
        } else {
            int kk = k - 96;
            if (g == 0)      v = ldmix(whh, (long)(jj)*96 + kk, m);
            else if (g == 1) v = ldmix(whh, (long)(96+jj)*96 + kk, m);
            else if (g == 3) v = ldmix(whh, (long)(192+jj)*96 + kk, m);
        }
        W2F[tid] = (_Float16)v;
    }
    if (tid < 96*128) {
        int j = tid >> 7, k = tid & 127;
        WinF[tid] = (_Float16)ldmix(w_in, (long)k*96 + j, m);
    }
    if (tid < 64*96) {
        int j = tid / 96, k = tid % 96;
        WoutF[tid] = (_Float16)ldmix(w_out, (long)k*OUTDIM + j, m);
    }
    if (tid < INDIM*16)   tau_w1_f[tid] = ldmix(tau_w1, tid, m);
    if (tid < HID)    smallf[tid]       = ldmix(b_in, tid, m);
    if (tid < 3*HID){ smallf[96+tid]    = ldmix(bih, tid, m);
                      smallf[384+tid]   = ldmix(bhh, tid, m); }
    if (tid < OUTDIM) smallf[672+tid]   = ldmix(b_out, tid, m);
    if (tid < 16)   { smallf[736+tid]   = ldmix(tau_w2, tid, m);
                      smallf[752+tid]   = ldmix(tau_b1, tid, m); }
    if (tid == 0)     smallf[768]       = ldmix(tau_b2, 0, m);
}

// ---------------- h0 = relu(x @ w_in + b_in) via fp16 MFMA -> hN (node layout, fp16) ----------------
__global__ void __launch_bounds__(512) h0_kernel(
        const void* __restrict__ x, const _Float16* __restrict__ WinF,
        const float* __restrict__ smallf, const int* __restrict__ mode,
        _Float16* __restrict__ hN, int N) {
    int row0 = blockIdx.x * BM;
    int jj0 = blockIdx.y * 16;

    __shared__ _Float16 Ah[128*136];
    __shared__ _Float16 Wh[16*136];

    int tid = threadIdx.x;
    int m = *mode;
    long limit = (long)N * INDIM;
    #pragma unroll
    for (int j = 0; j < 8; j++) {
        int e = (tid + j*512) * 4;
        int r = e >> 7, c = e & 127;
        long ge = (long)(row0 + r)*INDIM + c;
        half4 vh = {0, 0, 0, 0};
        if (ge + 4 <= limit) {
            if (m) {
                floatx4 v = *(const floatx4*)((const float*)x + ge);
                #pragma unroll
                for (int q = 0; q < 4; q++) vh[q] = (_Float16)v[q];
            } else {
                const __hip_bfloat16* p = (const __hip_bfloat16*)x + ge;
                #pragma unroll
                for (int q = 0; q < 4; q++) vh[q] = (_Float16)__bfloat162float(p[q]);
            }
        }
        *(half4*)(&Ah[r*136 + c]) = vh;
    }
    if (tid < 256) {
        int wrow = tid >> 4;
        int k = (tid & 15) * 8;
        *(half8*)(&Wh[wrow*136 + k]) = *(const half8*)(WinF + (long)(jj0 + wrow)*INDIM + k);
    }
    __syncthreads();

    int lane = tid & 63;
    int w = tid >> 6;
    int m15 = lane & 15, quad = lane >> 4;
    floatx4 acc = {0.f, 0.f, 0.f, 0.f};
    int abase = (w*16 + m15)*136 + quad*8;
    #pragma unroll
    for (int ks = 0; ks < 4; ks++) {
        int k0 = ks*32;
        half8 a = *(const half8*)(&Ah[abase + k0]);
        half8 b = *(const half8*)(&Wh[m15*136 + quad*8 + k0]);
        acc = __builtin_amdgcn_mfma_f32_16x16x32_f16(a, b, acc, 0, 0, 0);
    }

    int jj = jj0 + m15;
    float b = smallf[jj];
    #pragma unroll
    for (int reg = 0; reg < 4; reg++) {
        int li = row0 + w*16 + quad*4 + reg;
        if (li < N) hN[(long)li*HID + jj] = (_Float16)fmaxf(acc[reg] + b, 0.f);
    }
}

// ---------------- tau MLP -> steps (thread-per-node, x row in registers, weights via SMEM broadcast) ----------------
__global__ void __launch_bounds__(256) tau_kernel(
        const void* __restrict__ x, const float* __restrict__ tw,
        const float* __restrict__ smallf, const int* __restrict__ mode,
        int* __restrict__ steps, int N) {
    int n = blockIdx.x*blockDim.x + threadIdx.x;
    int m = *mode;
    int nc = (n < N) ? n : (N - 1);   // clamp: inactive lanes load valid memory

    float xr[128];
    if (m) {
        const floatx4* xp = (const floatx4*)x + (size_t)nc*32;
        #pragma unroll
        for (int ks = 0; ks < 32; ks++) {
            floatx4 v = xp[ks];
            xr[ks*4+0] = v[0]; xr[ks*4+1] = v[1];
            xr[ks*4+2] = v[2]; xr[ks*4+3] = v[3];
        }
    } else {
        const uintx4* xp = (const uintx4*)((const __hip_bfloat16*)x + (size_t)nc*128);
        #pragma unroll
        for (int ks = 0; ks < 16; ks++) {
            uintx4 v = xp[ks];
            #pragma unroll
            for (int q = 0; q < 4; q++) {
                unsigned int w = v[q];
                xr[ks*8 + q*2 + 0] = __uint_as_float((w & 0xFFFFu) << 16);
                xr[ks*8 + q*2 + 1] = __uint_as_float(w & 0xFFFF0000u);
            }
        }
    }

    float acc[16];
    #pragma unroll
    for (int j = 0; j < 16; j++) acc[j] = 0.f;
    #pragma unroll
    for (int k = 0; k < 128; k++) {
        float xv = xr[k];
        #pragma unroll
        for (int j = 0; j < 16; j++) acc[j] += xv * tw[k*16 + j];
    }

    float z = smallf[768];
    #pragma unroll
    for (int j = 0; j < 16; j++)
        z += fmaxf(acc[j] + smallf[752 + j], 0.f) * smallf[736 + j];
    float tau = fmaxf(z, 0.f) + log1pf(expf(-fabsf(z)));   // stable softplus
    float inv = 1.0f / tau;
    int s;
    if (inv >= 5.0f) s = 5;
    else { s = (int)inv; if (s < 0) s = 0; if (s > 5) s = 5; }
    if (n < N) steps[n] = s;
}

// ---------------- binned CSR build ----------------
// bin = row >> shift (shift=7 -> 128 nodes/bin). Packed edge: (local_row<<24) | col.
__global__ void __launch_bounds__(512) bincnt_kernel(
        const int* __restrict__ row, int E, int NB, int shift, int* __restrict__ bincnt) {
    __shared__ int h[NBF];
    int tid = threadIdx.x;
    int bs = blockDim.x;
    for (int i = tid; i < NB; i += bs) h[i] = 0;
    __syncthreads();
    int stride = gridDim.x * bs;
    for (int e = blockIdx.x*bs + tid; e < E; e += stride)
        atomicAdd(&h[row[e] >> shift], 1);
    __syncthreads();
    for (int i = tid; i < NB; i += bs) {
        int c = h[i];
        if (c) atomicAdd(&bincnt[i], c);
    }
}

__global__ void binscan_kernel(const int* __restrict__ bincnt, int NB, int E, int N,
                               int* __restrict__ bin_start, int* __restrict__ bincur,
                               int* __restrict__ off) {
    __shared__ int vals[NBF];
    __shared__ int part[256];
    int tid = threadIdx.x;
    int per = (NB + 255) / 256;
    int base = tid * per;
    int s = 0;
    for (int j = 0; j < per; j++) {
        int i = base + j;
        int v = (i < NB) ? bincnt[i] : 0;
        if (i < NBF) vals[i] = s;
        s += v;
    }
    part[tid] = s;
    __syncthreads();
    for (int ofs = 1; ofs < 256; ofs <<= 1) {
        int t = (tid >= ofs) ? part[tid - ofs] : 0;
        __syncthreads();
        part[tid] += t;
        __syncthreads();
    }
    int add = (tid == 0) ? 0 : part[tid - 1];
    for (int j = 0; j < per; j++) {
        int i = base + j;
        if (i < NB) {
            int v = vals[i] + add;
            bin_start[i] = v;
            bincur[i] = v;
        }
    }
    if (tid == 0) { bin_start[NB] = E; off[N] = E; }
}

__global__ void __launch_bounds__(512) binfill_kernel(
        const int* __restrict__ row, const int* __restrict__ col,
        int E, int NB, int shift, int* __restrict__ bincur,
        unsigned int* __restrict__ binbuf) {
    __shared__ int h[NBF];
    __shared__ int bs[NBF];
    int tid = threadIdx.x;
    int bsz = blockDim.x;
    int chunk = (E + gridDim.x - 1) / gridDim.x;
    int c0 = blockIdx.x * chunk;
    int c1 = min(c0 + chunk, E);
    for (int i = tid; i < NB; i += bsz) h[i] = 0;
    __syncthreads();
    for (int e = c0 + tid; e < c1; e += bsz)
        atomicAdd(&h[row[e] >> shift], 1);
    __syncthreads();
    for (int i = tid; i < NB; i += bsz) {
        int c = h[i];
        if (c) { bs[i] = atomicAdd(&bincur[i], c); h[i] = 0; }
    }
    __syncthreads();
    unsigned int mask = (1u << shift) - 1u;
    for (int e = c0 + tid; e < c1; e += bsz) {
        int r = row[e];
        int b = r >> shift;
        int p = atomicAdd(&h[b], 1);
        binbuf[bs[b] + p] = ((unsigned int)(r & mask) << 24) | (unsigned int)col[e];
    }
}

__global__ void __launch_bounds__(256) bincsr_kernel(
        const unsigned int* __restrict__ binbuf,
        const int* __restrict__ bin_start, int N, int shift,
        int* __restrict__ off, int* __restrict__ csr_col) {
    __shared__ int hist[256];
    __shared__ int pfx[256];
    int b = blockIdx.x;
    int tid = threadIdx.x;
    int BINSZ = 1 << shift;
    int s0 = bin_start[b], s1 = bin_start[b + 1];
    if (tid < BINSZ) hist[tid] = 0;
    __syncthreads();
    for (int e = s0 + tid; e < s1; e += 256)
        atomicAdd(&hist[binbuf[e] >> 24], 1);
    __syncthreads();
    if (tid == 0) {
        int run = 0;
        for (int j = 0; j < BINSZ; j++) { pfx[j] = run; run += hist[j]; }
    }
    __syncthreads();
    if (tid < BINSZ) {
        int node = (b << shift) + tid;
        if (node < N) off[node] = s0 + pfx[tid];
        hist[tid] = pfx[tid];   // cursor starts at local prefix
    }
    __syncthreads();
    for (int e = s0 + tid; e < s1; e += 256) {
        unsigned int pk = binbuf[e];
        int lr = pk >> 24;
        int p = atomicAdd(&hist[lr], 1);
        csr_col[s0 + p] = (int)(pk & 0xFFFFFFu);
    }
}

// ---------------- multi-block deterministic bucket pipeline (steps only) ----------------
__global__ void partial_kernel(const int* __restrict__ steps, int N, int C,
                               int* __restrict__ blksum) {
    __shared__ int red[256*8];
    int tid = threadIdx.x;
    int tg = blockIdx.x*256 + tid;
    int start = tg*C, end = min(start + C, N);
    if (end < start) end = start;
    int cnt[6] = {0,0,0,0,0,0};
    for (int i = start; i < end; i++) cnt[steps[i]]++;
    #pragma unroll
    for (int k = 0; k < 6; k++) red[tid*8 + k] = cnt[k];
    __syncthreads();
    for (int ofs = 128; ofs > 0; ofs >>= 1) {
        if (tid < ofs) {
            #pragma unroll
            for (int k = 0; k < 6; k++) red[tid*8 + k] += red[(tid+ofs)*8 + k];
        }
        __syncthreads();
    }
    if (tid < 6) blksum[blockIdx.x*8 + tid] = red[tid];
}

__global__ void base_kernel(const int* __restrict__ blksum, int* __restrict__ bstart,
                            int* __restrict__ blkbase) {
    __shared__ int tot[8];
    __shared__ int sb[8];
    int tid = threadIdx.x;
    if (tid < 6) {
        int s = 0;
        for (int b = 0; b < GP; b++) s += blksum[b*8 + tid];
        tot[tid] = s;
    }
    __syncthreads();
    if (tid == 0) {
        int run = 0;
        for (int ss = 5; ss >= 0; --ss) { sb[ss] = run; bstart[ss] = run; run += tot[ss]; }
        bstart[6] = run;          // = N
    }
    __syncthreads();
    if (tid < 6) {
        int run = sb[tid];
        for (int b = 0; b < GP; b++) { blkbase[b*8 + tid] = run; run += blksum[b*8 + tid]; }
    }
}

__global__ void scatter_kernel(const int* __restrict__ steps, const int* __restrict__ blkbase,
                               int N, int C, int* __restrict__ order) {
    __shared__ int buf[256];
    int tid = threadIdx.x;
    int b = blockIdx.x;
    int tg = b*256 + tid;
    int start = tg*C, end = min(start + C, N);
    if (end < start) end = start;
    int cnt[6] = {0,0,0,0,0,0};
    for (int i = start; i < end; i++) cnt[steps[i]]++;
    int mybase[6];
    #pragma unroll
    for (int k = 0; k < 6; k++) {
        buf[tid] = cnt[k];
        __syncthreads();
        for (int ofs = 1; ofs < 256; ofs <<= 1) {
            int t = (tid >= ofs) ? buf[tid - ofs] : 0;
            __syncthreads();
            buf[tid] += t;
            __syncthreads();
        }
        mybase[k] = blkbase[b*8 + k] + buf[tid] - cnt[k];
        __syncthreads();
    }
    for (int i = start; i < end; i++) order[mybase[steps[i]]++] = i;
}

// ---------------- pack hN into order-space fp16 plane (half8 vectorized) ----------------
__global__ void pack_kernel(const _Float16* __restrict__ hN, const int* __restrict__ order,
                            _Float16* __restrict__ hF, int N) {
    int tid = blockIdx.x*blockDim.x + threadIdx.x;
    if (tid >= N*12) return;
    int li = tid / 12, fg = tid % 12;
    int n = order[li];
    *(half8*)(hF + (size_t)li*HID + fg*8) = *(const half8*)(hN + (size_t)n*HID + fg*8);
}

// ---------------- aggregation: half8 gathers (16B/lane), fp32 accumulate -> packed fp16 aggF ----------------
// 8-edge unroll: 8x16B gathers + 8 col loads in flight per thread for latency hiding.
__global__ void agg_kernel(const _Float16* __restrict__ hN, const int* __restrict__ off,
                           const int* __restrict__ csr_col, const int* __restrict__ order,
                           const int* __restrict__ bstart, int t, _Float16* __restrict__ aggF) {
    int K = bstart[t];
    int total = K * 12;                       // 12 half8 groups per node
    int stride = gridDim.x * blockDim.x;
    for (int idx = blockIdx.x*blockDim.x + threadIdx.x; idx < total; idx += stride) {
        int li = idx / 12, fg = idx % 12;
        int f = fg * 8;
        int i = order[li];
        half8 hv = *(const half8*)(hN + (size_t)i*HID + f);
        float hvf[8];
        #pragma unroll
        for (int q = 0; q < 8; q++) hvf[q] = (float)hv[q];
        int e0 = off[i], e1 = off[i+1];
        float acc[8];
        #pragma unroll
        for (int q = 0; q < 8; q++) acc[q] = 0.f;
        int e = e0;
        for (; e + 8 <= e1; e += 8) {
            int c[8];
            #pragma unroll
            for (int u = 0; u < 8; u++) c[u] = csr_col[e + u];
            half8 v[8];
            #pragma unroll
            for (int u = 0; u < 8; u++) v[u] = *(const half8*)(hN + (size_t)c[u]*HID + f);
            #pragma unroll
            for (int u = 0; u < 8; u++) {
                #pragma unroll
                for (int q = 0; q < 8; q++) acc[q] += fabsf(hvf[q] - (float)v[u][q]);
            }
        }
        for (; e + 4 <= e1; e += 4) {
            int c0 = csr_col[e],   c1 = csr_col[e+1];
            int c2 = csr_col[e+2], c3 = csr_col[e+3];
            half8 v0 = *(const half8*)(hN + (size_t)c0*HID + f);
            half8 v1 = *(const half8*)(hN + (size_t)c1*HID + f);
            half8 v2 = *(const half8*)(hN + (size_t)c2*HID + f);
            half8 v3 = *(const half8*)(hN + (size_t)c3*HID + f);
            #pragma unroll
            for (int q = 0; q < 8; q++) {
                acc[q] += fabsf(hvf[q] - (float)v0[q]) + fabsf(hvf[q] - (float)v1[q])
                        + fabsf(hvf[q] - (float)v2[q]) + fabsf(hvf[q] - (float)v3[q]);
            }
        }
        for (; e < e1; e++) {
            int c = csr_col[e];
            half8 v = *(const half8*)(hN + (size_t)c*HID + f);
            #pragma unroll
            for (int q = 0; q < 8; q++) acc[q] += fabsf(hvf[q] - (float)v[q]);
        }
        half8 outv;
        #pragma unroll
        for (int q = 0; q < 8; q++) outv[q] = (_Float16)acc[q];
        *(half8*)(aggF + (size_t)li*HID + f) = outv;
    }
}

// ---------------- GRU via fp16 MFMA GEMM, fused epilogue + direct commit ----------------
__global__ void __launch_bounds__(512) gru_kernel(
        const _Float16* __restrict__ aggF, const _Float16* __restrict__ hFin,
        const _Float16* __restrict__ W2F,
        const float* __restrict__ smallf, const int* __restrict__ bstart, int t,
        const int* __restrict__ order, _Float16* __restrict__ hN,
        _Float16* __restrict__ hFout, int N) {
    int K = bstart[t];
    int row0 = blockIdx.x * BM;
    if (row0 >= K) return;
    int jj0 = blockIdx.y * 16;

    __shared__ _Float16 Ah[128*200];   // [agg|h] 128 x (192+8)
    __shared__ _Float16 Wh[64*200];    // 64 cols x (192+8)

    int tid = threadIdx.x;
    long limit = (long)N * HID;
    #pragma unroll
    for (int j = 0; j < 3; j++) {
        int e = (tid + j*512) * 8;
        {
            int r = e / 96, c = e % 96;
            long ge = (long)(row0 + r)*96 + c;
            half8 va = {0,0,0,0,0,0,0,0}, vh = va;
            if (ge + 8 <= limit) {
                va = *(const half8*)(aggF + ge);
                vh = *(const half8*)(hFin + ge);
            }
            *(half8*)(&Ah[r*200 + c])      = va;
            *(half8*)(&Ah[r*200 + 96 + c]) = vh;
        }
        {
            int wrow = e / 192, k = e % 192;
            int g = wrow >> 4, cc = wrow & 15;
            *(half8*)(&Wh[wrow*200 + k]) = *(const half8*)(W2F + (long)(g*96 + jj0 + cc)*192 + k);
        }
    }
    __syncthreads();

    int lane = tid & 63;
    int w = tid >> 6;
    int m15 = lane & 15, quad = lane >> 4;
    floatx4 acc[4];
    #pragma unroll
    for (int g = 0; g < 4; g++) acc[g] = (floatx4){0.f, 0.f, 0.f, 0.f};

    int abase = (w*16 + m15)*200 + quad*8;
    #pragma unroll
    for (int ks = 0; ks < 6; ks++) {
        int k0 = ks*32;
        half8 a = *(const half8*)(&Ah[abase + k0]);
        #pragma unroll
        for (int g = 0; g < 4; g++) {
            half8 b = *(const half8*)(&Wh[(g*16 + m15)*200 + quad*8 + k0]);
            acc[g] = __builtin_amdgcn_mfma_f32_16x16x32_f16(a, b, acc[g], 0, 0, 0);
        }
    }

    int jj = jj0 + m15;
    float bir = smallf[96+jj],  biz = smallf[192+jj], bin = smallf[288+jj];
    float bhr = smallf[384+jj], bhz = smallf[480+jj], bhn = smallf[576+jj];
    #pragma unroll
    for (int reg = 0; reg < 4; reg++) {
        int li = row0 + w*16 + quad*4 + reg;
        if (li < K) {
            float rp = acc[0][reg] + bir + bhr;
            float zp = acc[1][reg] + biz + bhz;
            float ip = acc[2][reg] + bin;
            float hn = acc[3][reg] + bhn;
            float r  = 1.f/(1.f + expf(-rp));
            float z  = 1.f/(1.f + expf(-zp));
            float nn = tanhf(ip + r*hn);
            int tr = w*16 + quad*4 + reg;             // row within tile
            float hold = (float)Ah[tr*200 + 96 + jj]; // h_old from LDS A-tile
            _Float16 v16 = (_Float16)((1.f - z)*nn + z*hold);
            int node = order[li];
            hN[(long)node*HID + jj] = v16;
            hFout[(long)li*HID + jj] = v16;
        }
    }
}

// ---------------- out = h @ w_out + b_out via fp16 MFMA ----------------
__global__ void __launch_bounds__(512) out_kernel(
        const _Float16* __restrict__ hN, const _Float16* __restrict__ WoutF,
        const float* __restrict__ smallf, void* out, const int* mode, int N) {
    int row0 = blockIdx.x * BM;
    int jj0 = blockIdx.y * 16;

    __shared__ _Float16 Ah[128*104];
    __shared__ _Float16 Wh[16*104];

    int tid = threadIdx.x;
    long limit = (long)N * HID;
    #pragma unroll
    for (int j = 0; j < 3; j++) {
        int e = (tid + j*512) * 8;        // 12288 elems per tile
        int r = e / 96, c = e % 96;
        long ge = (long)(row0 + r)*HID + c;
        half8 v = {0,0,0,0,0,0,0,0};
        if (ge + 8 <= limit) v = *(const half8*)(hN + ge);
        *(half8*)(&Ah[r*104 + c]) = v;
    }
    if (tid < 192) {
        int wrow = tid / 12;
        int k = (tid % 12) * 8;
        *(half8*)(&Wh[wrow*104 + k]) = *(const half8*)(WoutF + (long)(jj0 + wrow)*HID + k);
    }
    __syncthreads();

    int lane = tid & 63;
    int w = tid >> 6;
    int m15 = lane & 15, quad = lane >> 4;
    floatx4 acc = {0.f, 0.f, 0.f, 0.f};
    int abase = (w*16 + m15)*104 + quad*8;
    #pragma unroll
    for (int ks = 0; ks < 3; ks++) {
        int k0 = ks*32;
        half8 a = *(const half8*)(&Ah[abase + k0]);
        half8 b = *(const half8*)(&Wh[m15*104 + quad*8 + k0]);
        acc = __builtin_amdgcn_mfma_f32_16x16x32_f16(a, b, acc, 0, 0, 0);
    }

    int jj = jj0 + m15;
    float b = smallf[672+jj];
    int m = *mode;
    #pragma unroll
    for (int reg = 0; reg < 4; reg++) {
        int li = row0 + w*16 + quad*4 + reg;
        if (li < N) {
            float v = acc[reg] + b;
            long oi = (long)li*OUTDIM + jj;
            if (m) ((float*)out)[oi] = v;
            else   ((__hip_bfloat16*)out)[oi] = __float2bfloat16(v);
        }
    }
}

extern "C" void kernel_launch(void* const* d_in, const int* in_sizes, int n_in,
                              void* d_out, int out_size, void* d_ws, size_t ws_size,
                              hipStream_t stream) {
    const void* x      = d_in[0];
    const int*  ei     = (const int*)d_in[1];
    const void* w_in   = d_in[2],  *b_in   = d_in[3];
    const void* tau_w1 = d_in[4],  *tau_b1 = d_in[5];
    const void* tau_w2 = d_in[6],  *tau_b2 = d_in[7];
    const void* wih    = d_in[8],  *whh    = d_in[9];
    const void* bih    = d_in[10], *bhh    = d_in[11];
    const void* w_out  = d_in[12], *b_out  = d_in[13];

    int N = in_sizes[0] / INDIM;
    int E = in_sizes[1] / 2;
    const int* row = ei;
    const int* col = ei + E;

    // bin sizing: 128 nodes/bin (shift=7); widen if N too large for NBF bins
    int shift = 7;
    while ((((N + (1 << shift) - 1) >> shift)) > NBF && shift < 8) shift++;
    int NB = (N + (1 << shift) - 1) >> shift;

    char* ws = (char*)d_ws;
    size_t o = 0;
    auto take = [&](size_t bytes) -> char* {
        char* p = ws + o;
        o = (o + bytes + 255) & ~(size_t)255;
        return p;
    };
    _Float16* hN    = (_Float16*)take((size_t)N*HID*2);
    _Float16* hFa   = (_Float16*)take((size_t)N*HID*2);
    _Float16* hFb   = (_Float16*)take((size_t)N*HID*2);
    _Float16* aggF  = (_Float16*)take((size_t)N*HID*2);
    _Float16* W2F   = (_Float16*)take((size_t)384*192*2);
    _Float16* WinF  = (_Float16*)take((size_t)96*128*2);
    _Float16* WoutF = (_Float16*)take((size_t)64*96*2);
    float* tau_w1_f = (float*)take((size_t)INDIM*16*4);
    float* smallf   = (float*)take(1024*4);
    int*   off      = (int*)take((size_t)(N+1)*4);
    int*   csr_col  = (int*)take((size_t)E*4);
    int*   order    = (int*)take((size_t)N*4);
    int*   steps    = (int*)take((size_t)N*4);
    int*   bstart   = (int*)take(64);
    int*   mode     = (int*)take(64);
    int*   blksum   = (int*)take((size_t)GP*8*4);
    int*   blkbase  = (int*)take((size_t)GP*8*4);
    unsigned int* binbuf = (unsigned int*)take((size_t)E*4);
    int*   bin_start = (int*)take((size_t)(NBF+1)*4);
    int*   bincur    = (int*)take((size_t)NBF*4);
    char*  zbase    = ws + o;
    int*   bincnt   = (int*)take((size_t)NBF*4);
    size_t zbytes   = (size_t)((ws + o) - zbase);

    hipMemsetAsync(zbase, 0, zbytes, stream);
    sniff_kernel<<<1, 64, 0, stream>>>((const unsigned int*)x, mode);

    prep_kernel<<<(384*192 + 255)/256, 256, 0, stream>>>(
        w_in, b_in, tau_w1, tau_b1, tau_w2, tau_b2, wih, whh, bih, bhh, w_out, b_out,
        W2F, WinF, WoutF, tau_w1_f, smallf, mode);

    dim3 hgrid((N + BM - 1)/BM, 6);
    h0_kernel<<<hgrid, 512, 0, stream>>>(x, WinF, smallf, mode, hN, N);
    tau_kernel<<<(N + 255)/256, 256, 0, stream>>>(x, tau_w1_f, smallf, mode, steps, N);

    // binned CSR build
    bincnt_kernel<<<256, 512, 0, stream>>>(row, E, NB, shift, bincnt);
    binscan_kernel<<<1, 256, 0, stream>>>(bincnt, NB, E, N, bin_start, bincur, off);
    binfill_kernel<<<256, 512, 0, stream>>>(row, col, E, NB, shift, bincur, binbuf);
    bincsr_kernel<<<NB, 256, 0, stream>>>(binbuf, bin_start, N, shift, off, csr_col);

    int C = (N + GP*256 - 1) / (GP*256);
    partial_kernel<<<GP, 256, 0, stream>>>(steps, N, C, blksum);
    base_kernel<<<1, 64, 0, stream>>>(blksum, bstart, blkbase);
    scatter_kernel<<<GP, 256, 0, stream>>>(steps, blkbase, N, C, order);

    pack_kernel<<<(N*12 + 255)/256, 256, 0, stream>>>(hN, order, hFa, N);

    dim3 ggrid((N + BM - 1)/BM, 6);
    _Float16* hin = hFa;
    _Float16* hout = hFb;
    for (int t = 0; t < 5; t++) {
        agg_kernel<<<4096, 256, 0, stream>>>(hN, off, csr_col, order, bstart, t, aggF);
        gru_kernel<<<ggrid, 512, 0, stream>>>(aggF, hin, W2F, smallf, bstart, t,
                                              order, hN, hout, N);
        _Float16* tmp = hin; hin = hout; hout = tmp;
    }

    dim3 ogrid((N + BM - 1)/BM, 4);
    out_kernel<<<ogrid, 512, 0, stream>>>(hN, WoutF, smallf, d_out, mode, N);
}